// Round 8
// baseline (52.704 us; speedup 1.0000x reference)
//
#include <hip/hip_runtime.h>
#include <math.h>

#define H 1024
#define V 50257
#define NQ (V / 4)                 // 12564 full quads + 1 tail element
#define NBLK ((V + 15) / 16)       // 3142 logits blocks (16 rows each)
#define NPART (NBLK * 4)           // 12568 per-WAVE exp partials

// ws layout (float indices)
#define WS_HNEW   0                // H floats
#define WS_LOGITS H                // V floats (ends at 51281)
#define WS_PART   51328            // NPART per-wave exp partials

__device__ __forceinline__ float sigmoidf_(float x) { return 1.0f / (1.0f + expf(-x)); }

// Kernel 1: GRU cell -> h_new. 512 blocks; block b computes outputs b and
// b+512 (12 row-dots, 14 independent float4 loads per lane in flight).
__global__ __launch_bounds__(256) void gru_kernel(
    const int* __restrict__ inputs, const float* __restrict__ hidden,
    const float* __restrict__ tau, const float* __restrict__ emb,
    const float* __restrict__ w_ih, const float* __restrict__ w_hh,
    const float* __restrict__ b_ih, const float* __restrict__ b_hh,
    const float* __restrict__ theta, const float* __restrict__ mu,
    float* __restrict__ h_new_ws, float* __restrict__ h_new_out)
{
    const int i0 = blockIdx.x;        // 0..511
    const int i1 = i0 + 512;
    const int t = threadIdx.x;        // 0..255
    const int ix = inputs[0];
    const float prob = sigmoidf_(theta[ix] + mu[ix] * tau[0]);

    const float4 xe = ((const float4*)(emb + (size_t)ix * H))[t];
    const float4 hv = ((const float4*)hidden)[t];
    const float4 xv = make_float4(xe.x * prob, xe.y * prob, xe.z * prob, xe.w * prob);

    const float4* rows[12];
    rows[0]  = (const float4*)(w_ih + (size_t)(i0        ) * H);
    rows[1]  = (const float4*)(w_hh + (size_t)(i0        ) * H);
    rows[2]  = (const float4*)(w_ih + (size_t)(i0 +     H) * H);
    rows[3]  = (const float4*)(w_hh + (size_t)(i0 +     H) * H);
    rows[4]  = (const float4*)(w_ih + (size_t)(i0 + 2 * H) * H);
    rows[5]  = (const float4*)(w_hh + (size_t)(i0 + 2 * H) * H);
    rows[6]  = (const float4*)(w_ih + (size_t)(i1        ) * H);
    rows[7]  = (const float4*)(w_hh + (size_t)(i1        ) * H);
    rows[8]  = (const float4*)(w_ih + (size_t)(i1 +     H) * H);
    rows[9]  = (const float4*)(w_hh + (size_t)(i1 +     H) * H);
    rows[10] = (const float4*)(w_ih + (size_t)(i1 + 2 * H) * H);
    rows[11] = (const float4*)(w_hh + (size_t)(i1 + 2 * H) * H);

    float s[12];
    #pragma unroll
    for (int k = 0; k < 12; ++k) {
        const float4 w = rows[k][t];
        const float4 x = (k & 1) ? hv : xv;
        s[k] = w.x * x.x + w.y * x.y + w.z * x.z + w.w * x.w;
    }

    #pragma unroll
    for (int k = 0; k < 12; ++k)
        #pragma unroll
        for (int off = 32; off > 0; off >>= 1)
            s[k] += __shfl_down(s[k], off, 64);

    __shared__ float red[4][12];
    const int wave = t >> 6, lane = t & 63;
    if (lane == 0) {
        #pragma unroll
        for (int k = 0; k < 12; ++k) red[wave][k] = s[k];
    }
    __syncthreads();
    if (t < 2) {
        const int i = (t == 0) ? i0 : i1;
        const int o = t * 6;
        float v[6];
        #pragma unroll
        for (int k = 0; k < 6; ++k)
            v[k] = red[0][o + k] + red[1][o + k] + red[2][o + k] + red[3][o + k];
        const float r = sigmoidf_(v[0] + b_ih[i]          + v[1] + b_hh[i]);
        const float z = sigmoidf_(v[2] + b_ih[i + H]      + v[3] + b_hh[i + H]);
        const float n = tanhf(     v[4] + b_ih[i + 2 * H] + r * (v[5] + b_hh[i + 2 * H]));
        const float hn = (1.0f - z) * n + z * hidden[i];
        h_new_ws[i]  = hn;
        h_new_out[i] = hn;
    }
}

// Kernel 2: logits = w_lin @ h_new + b_lin. FOUR rows per wave, single shot:
// 16 independent w-loads in flight, four interleaved reduce chains, tail
// amortized over 4 rows. 16 rows/block, 3142 blocks. Per-WAVE exp partial
// (no LDS, no barrier -- waves retire independently).
__global__ __launch_bounds__(256) void logits_kernel(
    const float* __restrict__ w_lin, const float* __restrict__ b_lin,
    const float* __restrict__ h_new, float* __restrict__ logits,
    float* __restrict__ part)
{
    const int t = threadIdx.x;
    const int wave = t >> 6, lane = t & 63;
    const int rbase = blockIdx.x * 16 + wave * 4;

    int  r[4];
    bool val[4];
    #pragma unroll
    for (int j = 0; j < 4; ++j) {
        r[j] = rbase + j;
        val[j] = (r[j] < V);
        if (!val[j]) r[j] = V - 1;
    }

    const float4* hq = (const float4*)h_new;
    const float4 h0 = hq[lane], h1 = hq[lane + 64], h2 = hq[lane + 128], h3 = hq[lane + 192];

    float acc[4];
    #pragma unroll
    for (int j = 0; j < 4; ++j) {
        const float4* wr = (const float4*)(w_lin + (size_t)r[j] * H);
        const float4 w0 = wr[lane], w1 = wr[lane + 64], w2 = wr[lane + 128], w3 = wr[lane + 192];
        acc[j] = w0.x * h0.x + w0.y * h0.y + w0.z * h0.z + w0.w * h0.w
               + w1.x * h1.x + w1.y * h1.y + w1.z * h1.z + w1.w * h1.w
               + w2.x * h2.x + w2.y * h2.y + w2.z * h2.z + w2.w * h2.w
               + w3.x * h3.x + w3.y * h3.y + w3.z * h3.z + w3.w * h3.w;
    }

    #pragma unroll
    for (int off = 32; off > 0; off >>= 1) {
        #pragma unroll
        for (int j = 0; j < 4; ++j)
            acc[j] += __shfl_down(acc[j], off, 64);
    }

    if (lane == 0) {
        float e = 0.0f;
        #pragma unroll
        for (int j = 0; j < 4; ++j) {
            if (val[j]) {
                const float lg = acc[j] + b_lin[r[j]];
                logits[r[j]] = lg;
                e += expf(lg);    // logits ~[-3,3]: no max shift needed
            }
        }
        part[blockIdx.x * 4 + wave] = e;
    }
}

// Kernel 3: reduce the 12568 per-wave partials (50 KB, L2-hot, redundant per
// block), then finalize own contiguous 4096-elem chunk of out.
__global__ __launch_bounds__(1024) void lse_finalize_kernel(
    const float* __restrict__ part, const float* __restrict__ logits,
    float* __restrict__ out)
{
    const int t = threadIdx.x;
    const int wave = t >> 6, lane = t & 63;
    __shared__ float sm[16];

    float s = 0.0f;
    for (int k = t; k < NPART; k += 1024) s += part[k];
    #pragma unroll
    for (int off = 32; off > 0; off >>= 1)
        s += __shfl_down(s, off, 64);
    if (lane == 0) sm[wave] = s;
    __syncthreads();
    float tot = 0.0f;
    #pragma unroll
    for (int k = 0; k < 16; ++k) tot += sm[k];
    const float lse = logf(tot);

    const int gid = blockIdx.x * 1024 + t;
    if (gid < NQ) {
        const float4 x = ((const float4*)logits)[gid];
        ((float4*)out)[gid] = make_float4(x.x - lse, x.y - lse, x.z - lse, x.w - lse);
    } else if (gid == NQ) {
        out[V - 1] = logits[V - 1] - lse;
    }
}

extern "C" void kernel_launch(void* const* d_in, const int* in_sizes, int n_in,
                              void* d_out, int out_size, void* d_ws, size_t ws_size,
                              hipStream_t stream)
{
    const int*   inputs = (const int*)  d_in[0];
    const float* hidden = (const float*)d_in[1];
    const float* tau    = (const float*)d_in[2];
    const float* emb    = (const float*)d_in[3];
    const float* w_ih   = (const float*)d_in[4];
    const float* w_hh   = (const float*)d_in[5];
    const float* b_ih   = (const float*)d_in[6];
    const float* b_hh   = (const float*)d_in[7];
    const float* w_lin  = (const float*)d_in[8];
    const float* b_lin  = (const float*)d_in[9];
    const float* theta  = (const float*)d_in[10];
    const float* mu     = (const float*)d_in[11];

    float* out = (float*)d_out;          // [V log_softmax][H h_new]
    float* ws  = (float*)d_ws;
    float* h_new  = ws + WS_HNEW;
    float* logits = ws + WS_LOGITS;
    float* part   = ws + WS_PART;

    gru_kernel<<<H / 2, 256, 0, stream>>>(inputs, hidden, tau, emb, w_ih, w_hh,
                                          b_ih, b_hh, theta, mu, h_new, out + V);
    logits_kernel<<<NBLK, 256, 0, stream>>>(w_lin, b_lin, h_new, logits, part);
    lse_finalize_kernel<<<(NQ + 1023) / 1024, 1024, 0, stream>>>(part, logits, out);
}

// Round 9
// 44.409 us; speedup vs baseline: 1.1868x; 1.1868x over previous
//
#include <hip/hip_runtime.h>
#include <math.h>

#define H 1024
#define V 50257
#define NQ (V / 4)                 // 12564 full quads + 1 tail element
#define NPART ((V + 7) / 8)        // 6283 logits blocks / partials

// ws layout (float indices)
#define WS_HNEW   0                // H floats
#define WS_LOGITS H                // V floats (ends at 51281)
#define WS_PART   51328            // NPART per-block exp partials

typedef float f4 __attribute__((ext_vector_type(4)));

__device__ __forceinline__ float sigmoidf_(float x) { return 1.0f / (1.0f + expf(-x)); }
// Non-temporal 16B load: weight streams are read exactly once -> skip L2
// allocation (global_load_dwordx4 ... nt), keep h/logits/partials resident.
__device__ __forceinline__ f4 ntload4(const f4* p) { return __builtin_nontemporal_load(p); }
__device__ __forceinline__ float dot4(f4 a, f4 b) {
    return a.x * b.x + a.y * b.y + a.z * b.z + a.w * b.w;
}

// Kernel 1: GRU cell -> h_new. 512 blocks; block b computes outputs b and
// b+512 (12 row-dots, 14 independent float4 loads per lane in flight).
__global__ __launch_bounds__(256) void gru_kernel(
    const int* __restrict__ inputs, const float* __restrict__ hidden,
    const float* __restrict__ tau, const float* __restrict__ emb,
    const float* __restrict__ w_ih, const float* __restrict__ w_hh,
    const float* __restrict__ b_ih, const float* __restrict__ b_hh,
    const float* __restrict__ theta, const float* __restrict__ mu,
    float* __restrict__ h_new_ws, float* __restrict__ h_new_out)
{
    const int i0 = blockIdx.x;        // 0..511
    const int i1 = i0 + 512;
    const int t = threadIdx.x;        // 0..255
    const int ix = inputs[0];
    const float prob = sigmoidf_(theta[ix] + mu[ix] * tau[0]);

    const f4 xe = ((const f4*)(emb + (size_t)ix * H))[t];
    const f4 hv = ((const f4*)hidden)[t];
    const f4 xv = xe * prob;

    const f4* rows[12];
    rows[0]  = (const f4*)(w_ih + (size_t)(i0        ) * H);
    rows[1]  = (const f4*)(w_hh + (size_t)(i0        ) * H);
    rows[2]  = (const f4*)(w_ih + (size_t)(i0 +     H) * H);
    rows[3]  = (const f4*)(w_hh + (size_t)(i0 +     H) * H);
    rows[4]  = (const f4*)(w_ih + (size_t)(i0 + 2 * H) * H);
    rows[5]  = (const f4*)(w_hh + (size_t)(i0 + 2 * H) * H);
    rows[6]  = (const f4*)(w_ih + (size_t)(i1        ) * H);
    rows[7]  = (const f4*)(w_hh + (size_t)(i1        ) * H);
    rows[8]  = (const f4*)(w_ih + (size_t)(i1 +     H) * H);
    rows[9]  = (const f4*)(w_hh + (size_t)(i1 +     H) * H);
    rows[10] = (const f4*)(w_ih + (size_t)(i1 + 2 * H) * H);
    rows[11] = (const f4*)(w_hh + (size_t)(i1 + 2 * H) * H);

    float s[12];
    #pragma unroll
    for (int k = 0; k < 12; ++k) {
        const f4 w = ntload4(&rows[k][t]);   // weight rows: read-once -> nt
        const f4 x = (k & 1) ? hv : xv;
        s[k] = dot4(w, x);
    }

    #pragma unroll
    for (int k = 0; k < 12; ++k)
        #pragma unroll
        for (int off = 32; off > 0; off >>= 1)
            s[k] += __shfl_down(s[k], off, 64);

    __shared__ float red[4][12];
    const int wave = t >> 6, lane = t & 63;
    if (lane == 0) {
        #pragma unroll
        for (int k = 0; k < 12; ++k) red[wave][k] = s[k];
    }
    __syncthreads();
    if (t < 2) {
        const int i = (t == 0) ? i0 : i1;
        const int o = t * 6;
        float v[6];
        #pragma unroll
        for (int k = 0; k < 6; ++k)
            v[k] = red[0][o + k] + red[1][o + k] + red[2][o + k] + red[3][o + k];
        const float r = sigmoidf_(v[0] + b_ih[i]          + v[1] + b_hh[i]);
        const float z = sigmoidf_(v[2] + b_ih[i + H]      + v[3] + b_hh[i + H]);
        const float n = tanhf(     v[4] + b_ih[i + 2 * H] + r * (v[5] + b_hh[i + 2 * H]));
        const float hn = (1.0f - z) * n + z * hidden[i];
        h_new_ws[i]  = hn;
        h_new_out[i] = hn;
    }
}

// Kernel 2: logits = w_lin @ h_new + b_lin. TWO rows per wave, single shot
// (R7 structure -- measured optimum): 8 independent nt w-loads in flight,
// two interleaved reduce chains. 8 rows/block, 6283 blocks. Deterministic
// per-block exp-partial (logits ~[-3,3]: no max shift needed).
__global__ __launch_bounds__(256) void logits_kernel(
    const float* __restrict__ w_lin, const float* __restrict__ b_lin,
    const float* __restrict__ h_new, float* __restrict__ logits,
    float* __restrict__ part)
{
    const int t = threadIdx.x;
    const int wave = t >> 6, lane = t & 63;
    const int r0 = blockIdx.x * 8 + wave * 2;
    const int r1 = r0 + 1;
    const bool val0 = (r0 < V), val1 = (r1 < V);
    const int c0 = val0 ? r0 : (V - 1);
    const int c1 = val1 ? r1 : (V - 1);

    __shared__ float sm[4];

    const f4* hq  = (const f4*)h_new;
    const f4* wr0 = (const f4*)(w_lin + (size_t)c0 * H);
    const f4* wr1 = (const f4*)(w_lin + (size_t)c1 * H);

    const f4 a0 = ntload4(&wr0[lane]),       a1 = ntload4(&wr0[lane + 64]),
             a2 = ntload4(&wr0[lane + 128]), a3 = ntload4(&wr0[lane + 192]);
    const f4 b0 = ntload4(&wr1[lane]),       b1 = ntload4(&wr1[lane + 64]),
             b2 = ntload4(&wr1[lane + 128]), b3 = ntload4(&wr1[lane + 192]);
    const f4 h0 = hq[lane], h1 = hq[lane + 64], h2 = hq[lane + 128], h3 = hq[lane + 192];

    float acc0 = dot4(a0, h0) + dot4(a1, h1) + dot4(a2, h2) + dot4(a3, h3);
    float acc1 = dot4(b0, h0) + dot4(b1, h1) + dot4(b2, h2) + dot4(b3, h3);

    #pragma unroll
    for (int off = 32; off > 0; off >>= 1) {
        acc0 += __shfl_down(acc0, off, 64);
        acc1 += __shfl_down(acc1, off, 64);
    }

    if (lane == 0) {
        float e = 0.0f;
        if (val0) {
            const float lg = acc0 + b_lin[r0];
            logits[r0] = lg;
            e += expf(lg);
        }
        if (val1) {
            const float lg = acc1 + b_lin[r1];
            logits[r1] = lg;
            e += expf(lg);
        }
        sm[wave] = e;
    }
    __syncthreads();
    if (t == 0) part[blockIdx.x] = sm[0] + sm[1] + sm[2] + sm[3];
}

// Kernel 3: reduce the 6283 partials (25 KB, L2-hot, redundant per block),
// then finalize own contiguous 4096-elem chunk of out.
__global__ __launch_bounds__(1024) void lse_finalize_kernel(
    const float* __restrict__ part, const float* __restrict__ logits,
    float* __restrict__ out)
{
    const int t = threadIdx.x;
    const int wave = t >> 6, lane = t & 63;
    __shared__ float sm[16];

    float s = 0.0f;
    for (int k = t; k < NPART; k += 1024) s += part[k];
    #pragma unroll
    for (int off = 32; off > 0; off >>= 1)
        s += __shfl_down(s, off, 64);
    if (lane == 0) sm[wave] = s;
    __syncthreads();
    float tot = 0.0f;
    #pragma unroll
    for (int k = 0; k < 16; ++k) tot += sm[k];
    const float lse = logf(tot);

    const int gid = blockIdx.x * 1024 + t;
    if (gid < NQ) {
        const f4 x = ((const f4*)logits)[gid];
        f4 y; y.x = x.x - lse; y.y = x.y - lse; y.z = x.z - lse; y.w = x.w - lse;
        ((f4*)out)[gid] = y;
    } else if (gid == NQ) {
        out[V - 1] = logits[V - 1] - lse;
    }
}

extern "C" void kernel_launch(void* const* d_in, const int* in_sizes, int n_in,
                              void* d_out, int out_size, void* d_ws, size_t ws_size,
                              hipStream_t stream)
{
    const int*   inputs = (const int*)  d_in[0];
    const float* hidden = (const float*)d_in[1];
    const float* tau    = (const float*)d_in[2];
    const float* emb    = (const float*)d_in[3];
    const float* w_ih   = (const float*)d_in[4];
    const float* w_hh   = (const float*)d_in[5];
    const float* b_ih   = (const float*)d_in[6];
    const float* b_hh   = (const float*)d_in[7];
    const float* w_lin  = (const float*)d_in[8];
    const float* b_lin  = (const float*)d_in[9];
    const float* theta  = (const float*)d_in[10];
    const float* mu     = (const float*)d_in[11];

    float* out = (float*)d_out;          // [V log_softmax][H h_new]
    float* ws  = (float*)d_ws;
    float* h_new  = ws + WS_HNEW;
    float* logits = ws + WS_LOGITS;
    float* part   = ws + WS_PART;

    gru_kernel<<<H / 2, 256, 0, stream>>>(inputs, hidden, tau, emb, w_ih, w_hh,
                                          b_ih, b_hh, theta, mu, h_new, out + V);
    logits_kernel<<<NPART, 256, 0, stream>>>(w_lin, b_lin, h_new, logits, part);
    lse_finalize_kernel<<<(NQ + 1023) / 1024, 1024, 0, stream>>>(part, logits, out);
}